// Round 14
// baseline (56.668 us; speedup 1.0000x reference)
//
#include <hip/hip_runtime.h>

#define NPTS  131072        // B*G
#define GPTS  32768         // G

typedef __attribute__((ext_vector_type(4)))  _Float16 half4v;
typedef __attribute__((ext_vector_type(8)))  _Float16 half8v;
typedef __attribute__((ext_vector_type(16))) float    f32x16;

// ---- sigmoid emulating the reference f32 pipeline (bit-faithful) ----------
__device__ __forceinline__ float sigf(float x) {
    x = fminf(fmaxf(x, -9.21f), 9.21f);
    float t = (float)exp(-(double)x);
    return 1.0f / (1.0f + t);
}

// ---- fused front-end -------------------------------------------------------
// blocks [0,512):    sigmoid + per-block min + grid clear
// blocks [512,530):  W -> 32x32x16 f16 B-fragments
// blocks [530,2578): feats f32 -> f16 rows (+1 zero row)
__global__ __launch_bounds__(256) void k_front(const float* __restrict__ anchor,
                                               const float* __restrict__ W,
                                               const float* __restrict__ feats,
                                               float* __restrict__ s0a,
                                               float* __restrict__ s1a,
                                               float2* __restrict__ blockmin,
                                               _Float16* __restrict__ bpk,
                                               _Float16* __restrict__ fb,
                                               int* __restrict__ grd) {
    const int bid = blockIdx.x;
    if (bid < 512) {
        __shared__ float red[8];
        int i = bid * 256 + threadIdx.x;            // [0,131072)
        int2 mone = {-1, -1};
        ((int2*)grd)[i] = mone;                     // clear 1 MB rulebook grid
        float2 a = ((const float2*)anchor)[i];
        float s0 = sigf(a.x);
        float s1 = sigf(a.y);
        s0a[i] = s0;
        s1a[i] = s1;
        float m0 = s0, m1 = s1;
        #pragma unroll
        for (int off = 32; off; off >>= 1) {
            m0 = fminf(m0, __shfl_down(m0, off));
            m1 = fminf(m1, __shfl_down(m1, off));
        }
        int wv = threadIdx.x >> 6;
        if ((threadIdx.x & 63) == 0) { red[wv * 2] = m0; red[wv * 2 + 1] = m1; }
        __syncthreads();
        if (threadIdx.x == 0) {
            float a0 = fminf(fminf(red[0], red[2]), fminf(red[4], red[6]));
            float a1 = fminf(fminf(red[1], red[3]), fminf(red[5], red[7]));
            blockmin[bid] = make_float2(a0, a1);
        }
    } else if (bid < 530) {
        // frag q = t*8 + ks*2 + nt; lane l: B[k=ks*16+(l>>5)*8+j][n=nt*32+(l&31)]
        int tid = (bid - 512) * 256 + threadIdx.x;
        if (tid >= 4608) return;
        int l  = tid & 63;
        int q  = tid >> 6;
        int nt = q & 1;
        int ks = (q >> 1) & 3;
        int t  = q >> 3;
        int n  = nt * 32 + (l & 31);
        int kb = ks * 16 + (l >> 5) * 8;
        half8v v;
        #pragma unroll
        for (int j = 0; j < 8; ++j)
            v[j] = (_Float16)W[(t * 64 + kb + j) * 64 + n];
        ((half8v*)bpk)[q * 64 + l] = v;
    } else {
        int tid = (bid - 530) * 256 + threadIdx.x;  // [0,524288)
        if (bid == 530 && threadIdx.x < 8) {        // zero row NPTS
            half8v z = {};
            *(half8v*)(fb + (long)NPTS * 64 + threadIdx.x * 8) = z;
        }
        #pragma unroll
        for (int r = 0; r < 4; ++r) {
            long i = tid + (long)r * 524288;        // 2,097,152 float4 total
            float4 f = ((const float4*)feats)[i];
            half4v o = {(_Float16)f.x, (_Float16)f.y, (_Float16)f.z, (_Float16)f.w};
            *(half4v*)(fb + i * 4) = o;
        }
    }
}

// ---- cell index + rulebook scatter (max id wins); min-fold at head --------
__global__ __launch_bounds__(256) void k_grid(const float* __restrict__ s0a,
                                              const float* __restrict__ s1a,
                                              const float2* __restrict__ blockmin,
                                              int* __restrict__ pidx,
                                              int* __restrict__ grid) {
    __shared__ float red[8];
    float2 ba = blockmin[threadIdx.x];
    float2 bb = blockmin[threadIdx.x + 256];
    float m0 = fminf(ba.x, bb.x), m1 = fminf(ba.y, bb.y);
    #pragma unroll
    for (int off = 32; off; off >>= 1) {
        m0 = fminf(m0, __shfl_down(m0, off));
        m1 = fminf(m1, __shfl_down(m1, off));
    }
    int wv = threadIdx.x >> 6;
    if ((threadIdx.x & 63) == 0) { red[wv * 2] = m0; red[wv * 2 + 1] = m1; }
    __syncthreads();
    m0 = fminf(fminf(red[0], red[2]), fminf(red[4], red[6]));
    m1 = fminf(fminf(red[1], red[3]), fminf(red[5], red[7]));

    int i = blockIdx.x * 256 + threadIdx.x;
    int iy = (int)((s0a[i] - m0) * 256.0f);
    int ix = (int)((s1a[i] - m1) * 256.0f);
    pidx[i] = (iy << 8) | ix;
    int b = i >> 15;
    atomicMax(&grid[(b << 16) + (iy << 8) + ix], i);
}

// ---- MFMA conv with COALESCED A-gathers (R12 structure, higher occupancy) --
// Wave = 32 points x 64 couts, barrier-free tap loop (waves slip freely).
// Per tap: 4 global loads, 8 consecutive lanes fetch one 128B row (coalesced).
// Rows pass through SINGLE-buffered LDS (in-wave DS ordering makes dbuf
// unnecessary: deposit(t+1) is program-ordered after fragment-reads(t)),
// XOR-swizzled u^(row&7). LDS 20.5 KB/block + launch_bounds(256,6) ->
// 24 waves/CU (vs R12's 16) to hide the ~400cy random-gather tail.
// A-frag: lane l holds A[row=l&31][k=ks*16+(l>>5)*8+j].
// C/D: col=lane&31, row=(reg&3)+8*(reg>>2)+4*(lane>>5)   [HW-verified]
__global__ __launch_bounds__(256, 6) void k_mconv(const _Float16* __restrict__ fb,
                                                  const _Float16* __restrict__ bpk,
                                                  const int* __restrict__ pidx,
                                                  const int* __restrict__ grid,
                                                  float* __restrict__ out) {
    __shared__ int    nidb[4][9][32];               // 4.5 KB
    __shared__ half8v ash[4][32][8];                // 16 KB (single-buffered)

    const int lane  = threadIdx.x & 63;
    const int wv    = threadIdx.x >> 6;
    const int pbase = (blockIdx.x << 7) + (wv << 5);
    const int prow  = lane & 31;
    const int khalf = lane >> 5;

    // precompute all 9 neighbor ids for this wave's 32 points -> LDS
    if (lane < 32) {
        const int p  = pbase + lane;
        const int pk = pidx[p];
        const int iy = pk >> 8;
        const int ix = pk & 255;
        const int* gb = grid + ((p >> 15) << 16);
        #pragma unroll
        for (int t = 0; t < 9; ++t) {
            const int ny = iy + t / 3 - 1;
            const int nx = ix + t % 3 - 1;
            int n = ((unsigned)ny < 256u && (unsigned)nx < 256u) ? gb[(ny << 8) + nx] : -1;
            nidb[wv][t][lane] = (n < 0) ? NPTS : n;  // zero row for invalid taps
        }
    }
    __syncthreads();

    const int g  = lane >> 3;                        // row group 0..7
    const int u  = lane & 7;                         // 16B unit within row
    const int su = u ^ g;                            // swizzled write unit
    const int h  = prow & 7;                         // read-side swizzle key

    const half8v* bq = (const half8v*)bpk + lane;

    f32x16 acc0, acc1;
    #pragma unroll
    for (int r = 0; r < 16; ++r) { acc0[r] = 0.0f; acc1[r] = 0.0f; }

    // prefetch tap 0 rows (coalesced: 8 lanes cover one row's 128B line)
    half8v v0, v1, v2, v3;
    {
        int r0 = nidb[wv][0][g],      r1 = nidb[wv][0][8 + g];
        int r2 = nidb[wv][0][16 + g], r3 = nidb[wv][0][24 + g];
        v0 = ((const half8v*)(fb + ((long)r0 << 6)))[u];
        v1 = ((const half8v*)(fb + ((long)r1 << 6)))[u];
        v2 = ((const half8v*)(fb + ((long)r2 << 6)))[u];
        v3 = ((const half8v*)(fb + ((long)r3 << 6)))[u];
    }

    #pragma unroll
    for (int t = 0; t < 9; ++t) {
        // deposit tap t rows into LDS (swizzled); safe vs reads(t-1): in-wave
        // DS ops are ordered and the compiler preserves same-array aliasing
        ash[wv][g][su]      = v0;
        ash[wv][8 + g][su]  = v1;
        ash[wv][16 + g][su] = v2;
        ash[wv][24 + g][su] = v3;
        // prefetch tap t+1 (overlaps with MFMAs below)
        if (t < 8) {
            int r0 = nidb[wv][t + 1][g],      r1 = nidb[wv][t + 1][8 + g];
            int r2 = nidb[wv][t + 1][16 + g], r3 = nidb[wv][t + 1][24 + g];
            v0 = ((const half8v*)(fb + ((long)r0 << 6)))[u];
            v1 = ((const half8v*)(fb + ((long)r1 << 6)))[u];
            v2 = ((const half8v*)(fb + ((long)r2 << 6)))[u];
            v3 = ((const half8v*)(fb + ((long)r3 << 6)))[u];
        }
        // fragment reads (un-swizzle): identical data layout to R12
        half8v a0 = ash[wv][prow][(0 + khalf) ^ h];
        half8v a1 = ash[wv][prow][(2 + khalf) ^ h];
        half8v a2 = ash[wv][prow][(4 + khalf) ^ h];
        half8v a3 = ash[wv][prow][(6 + khalf) ^ h];
        const half8v* bt = bq + (t << 9);            // 8 frags * 64 lanes per tap
        acc0 = __builtin_amdgcn_mfma_f32_32x32x16_f16(a0, bt[0 * 64], acc0, 0, 0, 0);
        acc1 = __builtin_amdgcn_mfma_f32_32x32x16_f16(a0, bt[1 * 64], acc1, 0, 0, 0);
        acc0 = __builtin_amdgcn_mfma_f32_32x32x16_f16(a1, bt[2 * 64], acc0, 0, 0, 0);
        acc1 = __builtin_amdgcn_mfma_f32_32x32x16_f16(a1, bt[3 * 64], acc1, 0, 0, 0);
        acc0 = __builtin_amdgcn_mfma_f32_32x32x16_f16(a2, bt[4 * 64], acc0, 0, 0, 0);
        acc1 = __builtin_amdgcn_mfma_f32_32x32x16_f16(a2, bt[5 * 64], acc1, 0, 0, 0);
        acc0 = __builtin_amdgcn_mfma_f32_32x32x16_f16(a3, bt[6 * 64], acc0, 0, 0, 0);
        acc1 = __builtin_amdgcn_mfma_f32_32x32x16_f16(a3, bt[7 * 64], acc1, 0, 0, 0);
    }

    #pragma unroll
    for (int r = 0; r < 16; ++r) {
        int orow = pbase + (r & 3) + ((r >> 2) << 3) + (khalf << 2);
        out[(long)orow * 64 + prow]      = acc0[r];
        out[(long)orow * 64 + 32 + prow] = acc1[r];
    }
}

extern "C" void kernel_launch(void* const* d_in, const int* in_sizes, int n_in,
                              void* d_out, int out_size, void* d_ws, size_t ws_size,
                              hipStream_t stream) {
    const float* inst   = (const float*)d_in[0]; // (B,G,64)
    const float* anchor = (const float*)d_in[1]; // (B,G,2)
    const float* W      = (const float*)d_in[2]; // (3,3,64,64)
    float* out = (float*)d_out;

    char* ws = (char*)d_ws;
    float*     s0a  = (float*)(ws);                      // 512 KB
    float*     s1a  = (float*)(ws + 524288);             // 512 KB
    int*       pidx = (int*)(ws + 1048576);              // 512 KB
    int*       grd  = (int*)(ws + 1572864);              // 1 MB
    float2*    bmin = (float2*)(ws + 2621440);           // 4 KB (512 float2)
    _Float16*  fb   = (_Float16*)(ws + 2625536);         // (N+1)*64 f16
    _Float16*  bpk  = (_Float16*)(ws + 19402880);        // 72 KB

    k_front<<<2578, 256, 0, stream>>>(anchor, W, inst, s0a, s1a, bmin, bpk, fb, grd);
    k_grid <<<512,  256, 0, stream>>>(s0a, s1a, bmin, pidx, grd);
    k_mconv<<<1024, 256, 0, stream>>>(fb, bpk, pidx, grd, out);
}

// Round 15
// 48.555 us; speedup vs baseline: 1.1671x; 1.1671x over previous
//
#include <hip/hip_runtime.h>

#define NPTS  131072        // B*G
#define GPTS  32768         // G

typedef __attribute__((ext_vector_type(4)))  _Float16 half4v;
typedef __attribute__((ext_vector_type(8)))  _Float16 half8v;
typedef __attribute__((ext_vector_type(16))) float    f32x16;

// ---- sigmoid emulating the reference f32 pipeline (bit-faithful) ----------
__device__ __forceinline__ float sigf(float x) {
    x = fminf(fmaxf(x, -9.21f), 9.21f);
    float t = (float)exp(-(double)x);
    return 1.0f / (1.0f + t);
}

// ---- fused front-end -------------------------------------------------------
// blocks [0,512):    sigmoid + per-block min + grid clear
// blocks [512,530):  W -> 32x32x16 f16 B-fragments
// blocks [530,2578): feats f32 -> f16 rows (+1 zero row)
__global__ __launch_bounds__(256) void k_front(const float* __restrict__ anchor,
                                               const float* __restrict__ W,
                                               const float* __restrict__ feats,
                                               float* __restrict__ s0a,
                                               float* __restrict__ s1a,
                                               float2* __restrict__ blockmin,
                                               _Float16* __restrict__ bpk,
                                               _Float16* __restrict__ fb,
                                               int* __restrict__ grd) {
    const int bid = blockIdx.x;
    if (bid < 512) {
        __shared__ float red[8];
        int i = bid * 256 + threadIdx.x;            // [0,131072)
        int2 mone = {-1, -1};
        ((int2*)grd)[i] = mone;                     // clear 1 MB rulebook grid
        float2 a = ((const float2*)anchor)[i];
        float s0 = sigf(a.x);
        float s1 = sigf(a.y);
        s0a[i] = s0;
        s1a[i] = s1;
        float m0 = s0, m1 = s1;
        #pragma unroll
        for (int off = 32; off; off >>= 1) {
            m0 = fminf(m0, __shfl_down(m0, off));
            m1 = fminf(m1, __shfl_down(m1, off));
        }
        int wv = threadIdx.x >> 6;
        if ((threadIdx.x & 63) == 0) { red[wv * 2] = m0; red[wv * 2 + 1] = m1; }
        __syncthreads();
        if (threadIdx.x == 0) {
            float a0 = fminf(fminf(red[0], red[2]), fminf(red[4], red[6]));
            float a1 = fminf(fminf(red[1], red[3]), fminf(red[5], red[7]));
            blockmin[bid] = make_float2(a0, a1);
        }
    } else if (bid < 530) {
        // frag q = t*8 + ks*2 + nt; lane l: B[k=ks*16+(l>>5)*8+j][n=nt*32+(l&31)]
        int tid = (bid - 512) * 256 + threadIdx.x;
        if (tid >= 4608) return;
        int l  = tid & 63;
        int q  = tid >> 6;
        int nt = q & 1;
        int ks = (q >> 1) & 3;
        int t  = q >> 3;
        int n  = nt * 32 + (l & 31);
        int kb = ks * 16 + (l >> 5) * 8;
        half8v v;
        #pragma unroll
        for (int j = 0; j < 8; ++j)
            v[j] = (_Float16)W[(t * 64 + kb + j) * 64 + n];
        ((half8v*)bpk)[q * 64 + l] = v;
    } else {
        int tid = (bid - 530) * 256 + threadIdx.x;  // [0,524288)
        if (bid == 530 && threadIdx.x < 8) {        // zero row NPTS
            half8v z = {};
            *(half8v*)(fb + (long)NPTS * 64 + threadIdx.x * 8) = z;
        }
        #pragma unroll
        for (int r = 0; r < 4; ++r) {
            long i = tid + (long)r * 524288;        // 2,097,152 float4 total
            float4 f = ((const float4*)feats)[i];
            half4v o = {(_Float16)f.x, (_Float16)f.y, (_Float16)f.z, (_Float16)f.w};
            *(half4v*)(fb + i * 4) = o;
        }
    }
}

// ---- cell index + rulebook scatter (max id wins); min-fold at head --------
__global__ __launch_bounds__(256) void k_grid(const float* __restrict__ s0a,
                                              const float* __restrict__ s1a,
                                              const float2* __restrict__ blockmin,
                                              int* __restrict__ pidx,
                                              int* __restrict__ grid) {
    __shared__ float red[8];
    float2 ba = blockmin[threadIdx.x];
    float2 bb = blockmin[threadIdx.x + 256];
    float m0 = fminf(ba.x, bb.x), m1 = fminf(ba.y, bb.y);
    #pragma unroll
    for (int off = 32; off; off >>= 1) {
        m0 = fminf(m0, __shfl_down(m0, off));
        m1 = fminf(m1, __shfl_down(m1, off));
    }
    int wv = threadIdx.x >> 6;
    if ((threadIdx.x & 63) == 0) { red[wv * 2] = m0; red[wv * 2 + 1] = m1; }
    __syncthreads();
    m0 = fminf(fminf(red[0], red[2]), fminf(red[4], red[6]));
    m1 = fminf(fminf(red[1], red[3]), fminf(red[5], red[7]));

    int i = blockIdx.x * 256 + threadIdx.x;
    int iy = (int)((s0a[i] - m0) * 256.0f);
    int ix = (int)((s1a[i] - m1) * 256.0f);
    pidx[i] = (iy << 8) | ix;
    int b = i >> 15;
    atomicMax(&grid[(b << 16) + (iy << 8) + ix], i);
}

// ---- MFMA conv (R12 dataflow, higher occupancy, barrier-free) ---------------
// Wave = 32 points x 64 couts. Per tap: 4 coalesced global loads (8 lanes
// cover one 128B row), LDS double-buffered + XOR-swizzled u^(row&7).
// nid table -> 9 per-lane registers + __shfl at staging (no LDS, no barrier).
// Block = 128 thr (2 waves), LDS 16 KB -> 10 blocks/CU = 20 waves/CU.
// Fragments bit-identical to R12 -> absmax must stay 0.03125.
// A-frag: lane l holds A[row=l&31][k=ks*16+(l>>5)*8+j].
// C/D: col=lane&31, row=(reg&3)+8*(reg>>2)+4*(lane>>5)   [HW-verified]
__global__ __launch_bounds__(128, 5) void k_mconv(const _Float16* __restrict__ fb,
                                                  const _Float16* __restrict__ bpk,
                                                  const int* __restrict__ pidx,
                                                  const int* __restrict__ grid,
                                                  float* __restrict__ out) {
    __shared__ half8v ash[2][2][32][8];             // [wave][buf][row][unit] 16 KB

    const int lane  = threadIdx.x & 63;
    const int wv    = threadIdx.x >> 6;             // 0..1
    const int pbase = (blockIdx.x << 6) + (wv << 5);
    const int prow  = lane & 31;
    const int khalf = lane >> 5;
    const int p     = pbase + prow;

    // all 64 lanes compute the 9 nids of their point (lanes 32-63 mirror 0-31)
    const int pk = pidx[p];
    const int iy = pk >> 8;
    const int ix = pk & 255;
    const int* gb = grid + ((p >> 15) << 16);
    #define NID(t)                                                              \
        ({ int ny_ = iy + (t) / 3 - 1, nx_ = ix + (t) % 3 - 1;                  \
           int n_ = ((unsigned)ny_ < 256u && (unsigned)nx_ < 256u)              \
                      ? gb[(ny_ << 8) + nx_] : -1;                              \
           (n_ < 0) ? NPTS : n_; })
    int nid0 = NID(0), nid1 = NID(1), nid2 = NID(2), nid3 = NID(3), nid4 = NID(4);
    int nid5 = NID(5), nid6 = NID(6), nid7 = NID(7), nid8 = NID(8);
    #undef NID

    const int g  = lane >> 3;                        // row group 0..7
    const int u  = lane & 7;                         // 16B unit within row
    const int su = u ^ g;                            // swizzled write unit
    const int h  = prow & 7;                         // read-side swizzle key

    const half8v* bq = (const half8v*)bpk + lane;

    f32x16 acc0, acc1;
    #pragma unroll
    for (int r = 0; r < 16; ++r) { acc0[r] = 0.0f; acc1[r] = 0.0f; }

    half8v v0, v1, v2, v3;
    // prefetch rows of a tap: row index for group g taken from lane m*8+g
    #define PREF(nidt)                                                          \
        {                                                                       \
            int r0_ = __shfl(nidt, g);                                          \
            int r1_ = __shfl(nidt, 8 + g);                                      \
            int r2_ = __shfl(nidt, 16 + g);                                     \
            int r3_ = __shfl(nidt, 24 + g);                                     \
            v0 = ((const half8v*)(fb + ((long)r0_ << 6)))[u];                   \
            v1 = ((const half8v*)(fb + ((long)r1_ << 6)))[u];                   \
            v2 = ((const half8v*)(fb + ((long)r2_ << 6)))[u];                   \
            v3 = ((const half8v*)(fb + ((long)r3_ << 6)))[u];                   \
        }
    // one tap: deposit staged rows (buf), prefetch next, read frags, 16 MFMA
    #define TAP(t, buf, PREFETCH)                                               \
        {                                                                       \
            ash[wv][buf][g][su]      = v0;                                      \
            ash[wv][buf][8 + g][su]  = v1;                                      \
            ash[wv][buf][16 + g][su] = v2;                                      \
            ash[wv][buf][24 + g][su] = v3;                                      \
            PREFETCH                                                            \
            half8v a0 = ash[wv][buf][prow][(0 + khalf) ^ h];                    \
            half8v a1 = ash[wv][buf][prow][(2 + khalf) ^ h];                    \
            half8v a2 = ash[wv][buf][prow][(4 + khalf) ^ h];                    \
            half8v a3 = ash[wv][buf][prow][(6 + khalf) ^ h];                    \
            const half8v* bt = bq + ((t) << 9);                                 \
            acc0 = __builtin_amdgcn_mfma_f32_32x32x16_f16(a0, bt[0 * 64], acc0, 0, 0, 0); \
            acc1 = __builtin_amdgcn_mfma_f32_32x32x16_f16(a0, bt[1 * 64], acc1, 0, 0, 0); \
            acc0 = __builtin_amdgcn_mfma_f32_32x32x16_f16(a1, bt[2 * 64], acc0, 0, 0, 0); \
            acc1 = __builtin_amdgcn_mfma_f32_32x32x16_f16(a1, bt[3 * 64], acc1, 0, 0, 0); \
            acc0 = __builtin_amdgcn_mfma_f32_32x32x16_f16(a2, bt[4 * 64], acc0, 0, 0, 0); \
            acc1 = __builtin_amdgcn_mfma_f32_32x32x16_f16(a2, bt[5 * 64], acc1, 0, 0, 0); \
            acc0 = __builtin_amdgcn_mfma_f32_32x32x16_f16(a3, bt[6 * 64], acc0, 0, 0, 0); \
            acc1 = __builtin_amdgcn_mfma_f32_32x32x16_f16(a3, bt[7 * 64], acc1, 0, 0, 0); \
        }

    PREF(nid0)
    TAP(0, 0, PREF(nid1))
    TAP(1, 1, PREF(nid2))
    TAP(2, 0, PREF(nid3))
    TAP(3, 1, PREF(nid4))
    TAP(4, 0, PREF(nid5))
    TAP(5, 1, PREF(nid6))
    TAP(6, 0, PREF(nid7))
    TAP(7, 1, PREF(nid8))
    TAP(8, 0, )
    #undef TAP
    #undef PREF

    #pragma unroll
    for (int r = 0; r < 16; ++r) {
        int orow = pbase + (r & 3) + ((r >> 2) << 3) + (khalf << 2);
        out[(long)orow * 64 + prow]      = acc0[r];
        out[(long)orow * 64 + 32 + prow] = acc1[r];
    }
}

extern "C" void kernel_launch(void* const* d_in, const int* in_sizes, int n_in,
                              void* d_out, int out_size, void* d_ws, size_t ws_size,
                              hipStream_t stream) {
    const float* inst   = (const float*)d_in[0]; // (B,G,64)
    const float* anchor = (const float*)d_in[1]; // (B,G,2)
    const float* W      = (const float*)d_in[2]; // (3,3,64,64)
    float* out = (float*)d_out;

    char* ws = (char*)d_ws;
    float*     s0a  = (float*)(ws);                      // 512 KB
    float*     s1a  = (float*)(ws + 524288);             // 512 KB
    int*       pidx = (int*)(ws + 1048576);              // 512 KB
    int*       grd  = (int*)(ws + 1572864);              // 1 MB
    float2*    bmin = (float2*)(ws + 2621440);           // 4 KB (512 float2)
    _Float16*  fb   = (_Float16*)(ws + 2625536);         // (N+1)*64 f16
    _Float16*  bpk  = (_Float16*)(ws + 19402880);        // 72 KB

    k_front<<<2578, 256, 0, stream>>>(anchor, W, inst, s0a, s1a, bmin, bpk, fb, grd);
    k_grid <<<512,  256, 0, stream>>>(s0a, s1a, bmin, pidx, grd);
    k_mconv<<<2048, 128, 0, stream>>>(fb, bpk, pidx, grd, out);
}

// Round 16
// 45.177 us; speedup vs baseline: 1.2543x; 1.0748x over previous
//
#include <hip/hip_runtime.h>

#define NPTS  131072        // B*G
#define GPTS  32768         // G

typedef __attribute__((ext_vector_type(4)))  _Float16 half4v;
typedef __attribute__((ext_vector_type(8)))  _Float16 half8v;
typedef __attribute__((ext_vector_type(16))) float    f32x16;

// ---- sigmoid emulating the reference f32 pipeline (bit-faithful) ----------
__device__ __forceinline__ float sigf(float x) {
    x = fminf(fmaxf(x, -9.21f), 9.21f);
    float t = (float)exp(-(double)x);
    return 1.0f / (1.0f + t);
}

// ---- fused front-end -------------------------------------------------------
// blocks [0,512):    sigmoid + per-block min + grid clear
// blocks [512,530):  W -> 32x32x16 f16 B-fragments
// blocks [530,2578): feats f32 -> f16 rows (+1 zero row)
__global__ __launch_bounds__(256) void k_front(const float* __restrict__ anchor,
                                               const float* __restrict__ W,
                                               const float* __restrict__ feats,
                                               float* __restrict__ s0a,
                                               float* __restrict__ s1a,
                                               float2* __restrict__ blockmin,
                                               _Float16* __restrict__ bpk,
                                               _Float16* __restrict__ fb,
                                               int* __restrict__ grd) {
    const int bid = blockIdx.x;
    if (bid < 512) {
        __shared__ float red[8];
        int i = bid * 256 + threadIdx.x;            // [0,131072)
        int2 mone = {-1, -1};
        ((int2*)grd)[i] = mone;                     // clear 1 MB rulebook grid
        float2 a = ((const float2*)anchor)[i];
        float s0 = sigf(a.x);
        float s1 = sigf(a.y);
        s0a[i] = s0;
        s1a[i] = s1;
        float m0 = s0, m1 = s1;
        #pragma unroll
        for (int off = 32; off; off >>= 1) {
            m0 = fminf(m0, __shfl_down(m0, off));
            m1 = fminf(m1, __shfl_down(m1, off));
        }
        int wv = threadIdx.x >> 6;
        if ((threadIdx.x & 63) == 0) { red[wv * 2] = m0; red[wv * 2 + 1] = m1; }
        __syncthreads();
        if (threadIdx.x == 0) {
            float a0 = fminf(fminf(red[0], red[2]), fminf(red[4], red[6]));
            float a1 = fminf(fminf(red[1], red[3]), fminf(red[5], red[7]));
            blockmin[bid] = make_float2(a0, a1);
        }
    } else if (bid < 530) {
        // frag q = t*8 + ks*2 + nt; lane l: B[k=ks*16+(l>>5)*8+j][n=nt*32+(l&31)]
        int tid = (bid - 512) * 256 + threadIdx.x;
        if (tid >= 4608) return;
        int l  = tid & 63;
        int q  = tid >> 6;
        int nt = q & 1;
        int ks = (q >> 1) & 3;
        int t  = q >> 3;
        int n  = nt * 32 + (l & 31);
        int kb = ks * 16 + (l >> 5) * 8;
        half8v v;
        #pragma unroll
        for (int j = 0; j < 8; ++j)
            v[j] = (_Float16)W[(t * 64 + kb + j) * 64 + n];
        ((half8v*)bpk)[q * 64 + l] = v;
    } else {
        int tid = (bid - 530) * 256 + threadIdx.x;  // [0,524288)
        if (bid == 530 && threadIdx.x < 8) {        // zero row NPTS
            half8v z = {};
            *(half8v*)(fb + (long)NPTS * 64 + threadIdx.x * 8) = z;
        }
        #pragma unroll
        for (int r = 0; r < 4; ++r) {
            long i = tid + (long)r * 524288;        // 2,097,152 float4 total
            float4 f = ((const float4*)feats)[i];
            half4v o = {(_Float16)f.x, (_Float16)f.y, (_Float16)f.z, (_Float16)f.w};
            *(half4v*)(fb + i * 4) = o;
        }
    }
}

// ---- cell index + rulebook scatter (max id wins); min-fold at head --------
__global__ __launch_bounds__(256) void k_grid(const float* __restrict__ s0a,
                                              const float* __restrict__ s1a,
                                              const float2* __restrict__ blockmin,
                                              int* __restrict__ pidx,
                                              int* __restrict__ grid) {
    __shared__ float red[8];
    float2 ba = blockmin[threadIdx.x];
    float2 bb = blockmin[threadIdx.x + 256];
    float m0 = fminf(ba.x, bb.x), m1 = fminf(ba.y, bb.y);
    #pragma unroll
    for (int off = 32; off; off >>= 1) {
        m0 = fminf(m0, __shfl_down(m0, off));
        m1 = fminf(m1, __shfl_down(m1, off));
    }
    int wv = threadIdx.x >> 6;
    if ((threadIdx.x & 63) == 0) { red[wv * 2] = m0; red[wv * 2 + 1] = m1; }
    __syncthreads();
    m0 = fminf(fminf(red[0], red[2]), fminf(red[4], red[6]));
    m1 = fminf(fminf(red[1], red[3]), fminf(red[5], red[7]));

    int i = blockIdx.x * 256 + threadIdx.x;
    int iy = (int)((s0a[i] - m0) * 256.0f);
    int ix = (int)((s1a[i] - m1) * 256.0f);
    pidx[i] = (iy << 8) | ix;
    int b = i >> 15;
    atomicMax(&grid[(b << 16) + (iy << 8) + ix], i);
}

// ---- MFMA conv (R12-best structure + batch->XCD pinned block swizzle) ------
// Only delta vs R12: blockIdx remap so batch k is processed ONLY by XCDs
// 2k,2k+1 (dispatch round-robins bid%8 over XCDs). Each XCD's gather working
// set becomes one batch slice of fb (4.2 MB ~= its 4 MiB L2) -> random
// 128B row-gathers served from local L2 instead of cross-die L3 fabric.
// Wave = 32 points x 64 couts; coalesced A (8 lanes per 128B row) through
// double-buffered XOR-swizzled LDS. Fragments bit-identical to R12.
// A-frag: lane l holds A[row=l&31][k=ks*16+(l>>5)*8+j].
// C/D: col=lane&31, row=(reg&3)+8*(reg>>2)+4*(lane>>5)   [HW-verified]
__global__ __launch_bounds__(256, 4) void k_mconv(const _Float16* __restrict__ fb,
                                                  const _Float16* __restrict__ bpk,
                                                  const int* __restrict__ pidx,
                                                  const int* __restrict__ grid,
                                                  float* __restrict__ out) {
    __shared__ int    nidb[4][9][32];               // 4.5 KB
    __shared__ half8v ash[4][2][32][8];             // 32 KB (2-buf staging)

    const int lane  = threadIdx.x & 63;
    const int wv    = threadIdx.x >> 6;

    // batch->XCD pinning: xcd = bid&7 -> batch = xcd>>1; 256 blocks/batch
    const int xcd   = blockIdx.x & 7;
    const int pr    = blockIdx.x >> 3;               // [0,128)
    const int bat   = xcd >> 1;
    const int bib   = ((xcd & 1) << 7) + pr;         // block-in-batch [0,256)
    const int pbase = (bat << 15) + (bib << 7) + (wv << 5);

    const int prow  = lane & 31;
    const int khalf = lane >> 5;

    // precompute all 9 neighbor ids for this wave's 32 points -> LDS
    if (lane < 32) {
        const int p  = pbase + lane;
        const int pk = pidx[p];
        const int iy = pk >> 8;
        const int ix = pk & 255;
        const int* gb = grid + ((p >> 15) << 16);
        #pragma unroll
        for (int t = 0; t < 9; ++t) {
            const int ny = iy + t / 3 - 1;
            const int nx = ix + t % 3 - 1;
            int n = ((unsigned)ny < 256u && (unsigned)nx < 256u) ? gb[(ny << 8) + nx] : -1;
            nidb[wv][t][lane] = (n < 0) ? NPTS : n;  // zero row for invalid taps
        }
    }
    __syncthreads();

    const int g  = lane >> 3;                        // row group 0..7
    const int u  = lane & 7;                         // 16B unit within row
    const int su = u ^ g;                            // swizzled write unit
    const int h  = prow & 7;                         // read-side swizzle key

    const half8v* bq = (const half8v*)bpk + lane;

    f32x16 acc0, acc1;
    #pragma unroll
    for (int r = 0; r < 16; ++r) { acc0[r] = 0.0f; acc1[r] = 0.0f; }

    // prefetch tap 0 rows (coalesced: 8 lanes cover one row's 128B line)
    half8v v0, v1, v2, v3;
    {
        int r0 = nidb[wv][0][g],      r1 = nidb[wv][0][8 + g];
        int r2 = nidb[wv][0][16 + g], r3 = nidb[wv][0][24 + g];
        v0 = ((const half8v*)(fb + ((long)r0 << 6)))[u];
        v1 = ((const half8v*)(fb + ((long)r1 << 6)))[u];
        v2 = ((const half8v*)(fb + ((long)r2 << 6)))[u];
        v3 = ((const half8v*)(fb + ((long)r3 << 6)))[u];
    }

    #pragma unroll
    for (int t = 0; t < 9; ++t) {
        const int buf = t & 1;
        // deposit tap t rows into LDS (swizzled)
        ash[wv][buf][g][su]      = v0;
        ash[wv][buf][8 + g][su]  = v1;
        ash[wv][buf][16 + g][su] = v2;
        ash[wv][buf][24 + g][su] = v3;
        // prefetch tap t+1 (overlaps with MFMAs below)
        if (t < 8) {
            int r0 = nidb[wv][t + 1][g],      r1 = nidb[wv][t + 1][8 + g];
            int r2 = nidb[wv][t + 1][16 + g], r3 = nidb[wv][t + 1][24 + g];
            v0 = ((const half8v*)(fb + ((long)r0 << 6)))[u];
            v1 = ((const half8v*)(fb + ((long)r1 << 6)))[u];
            v2 = ((const half8v*)(fb + ((long)r2 << 6)))[u];
            v3 = ((const half8v*)(fb + ((long)r3 << 6)))[u];
        }
        // fragment reads (un-swizzle): identical data layout to R12
        half8v a0 = ash[wv][buf][prow][(0 + khalf) ^ h];
        half8v a1 = ash[wv][buf][prow][(2 + khalf) ^ h];
        half8v a2 = ash[wv][buf][prow][(4 + khalf) ^ h];
        half8v a3 = ash[wv][buf][prow][(6 + khalf) ^ h];
        const half8v* bt = bq + (t << 9);            // 8 frags * 64 lanes per tap
        acc0 = __builtin_amdgcn_mfma_f32_32x32x16_f16(a0, bt[0 * 64], acc0, 0, 0, 0);
        acc1 = __builtin_amdgcn_mfma_f32_32x32x16_f16(a0, bt[1 * 64], acc1, 0, 0, 0);
        acc0 = __builtin_amdgcn_mfma_f32_32x32x16_f16(a1, bt[2 * 64], acc0, 0, 0, 0);
        acc1 = __builtin_amdgcn_mfma_f32_32x32x16_f16(a1, bt[3 * 64], acc1, 0, 0, 0);
        acc0 = __builtin_amdgcn_mfma_f32_32x32x16_f16(a2, bt[4 * 64], acc0, 0, 0, 0);
        acc1 = __builtin_amdgcn_mfma_f32_32x32x16_f16(a2, bt[5 * 64], acc1, 0, 0, 0);
        acc0 = __builtin_amdgcn_mfma_f32_32x32x16_f16(a3, bt[6 * 64], acc0, 0, 0, 0);
        acc1 = __builtin_amdgcn_mfma_f32_32x32x16_f16(a3, bt[7 * 64], acc1, 0, 0, 0);
    }

    #pragma unroll
    for (int r = 0; r < 16; ++r) {
        int orow = pbase + (r & 3) + ((r >> 2) << 3) + (khalf << 2);
        out[(long)orow * 64 + prow]      = acc0[r];
        out[(long)orow * 64 + 32 + prow] = acc1[r];
    }
}

extern "C" void kernel_launch(void* const* d_in, const int* in_sizes, int n_in,
                              void* d_out, int out_size, void* d_ws, size_t ws_size,
                              hipStream_t stream) {
    const float* inst   = (const float*)d_in[0]; // (B,G,64)
    const float* anchor = (const float*)d_in[1]; // (B,G,2)
    const float* W      = (const float*)d_in[2]; // (3,3,64,64)
    float* out = (float*)d_out;

    char* ws = (char*)d_ws;
    float*     s0a  = (float*)(ws);                      // 512 KB
    float*     s1a  = (float*)(ws + 524288);             // 512 KB
    int*       pidx = (int*)(ws + 1048576);              // 512 KB
    int*       grd  = (int*)(ws + 1572864);              // 1 MB
    float2*    bmin = (float2*)(ws + 2621440);           // 4 KB (512 float2)
    _Float16*  fb   = (_Float16*)(ws + 2625536);         // (N+1)*64 f16
    _Float16*  bpk  = (_Float16*)(ws + 19402880);        // 72 KB

    k_front<<<2578, 256, 0, stream>>>(anchor, W, inst, s0a, s1a, bmin, bpk, fb, grd);
    k_grid <<<512,  256, 0, stream>>>(s0a, s1a, bmin, pidx, grd);
    k_mconv<<<1024, 256, 0, stream>>>(fb, bpk, pidx, grd, out);
}